// Round 2
// baseline (493.428 us; speedup 1.0000x reference)
//
#include <hip/hip_runtime.h>

#define A_ALLELES 4096
#define CCH 12     // input channels
#define LW 32      // read window length
#define DH 32      // hidden dim

// ---------------------------------------------------------------------------
// Kernel 1: exclusive prefix-sum of the two per-allele read-count arrays.
// ---------------------------------------------------------------------------
__global__ __launch_bounds__(256) void scan_kernel(
    const int* __restrict__ c0, const int* __restrict__ c1,
    int* __restrict__ o0, int* __restrict__ o1)
{
    const int* c = (blockIdx.x == 0) ? c0 : c1;
    int*       o = (blockIdx.x == 0) ? o0 : o1;

    __shared__ int part[256];
    const int tid  = threadIdx.x;
    const int base = tid * 16;

    int loc[16];
    int s = 0;
#pragma unroll
    for (int i = 0; i < 16; ++i) { loc[i] = c[base + i]; s += loc[i]; }
    part[tid] = s;
    __syncthreads();

    for (int st = 1; st < 256; st <<= 1) {
        int v = (tid >= st) ? part[tid - st] : 0;
        __syncthreads();
        part[tid] += v;
        __syncthreads();
    }

    int excl = (tid == 0) ? 0 : part[tid - 1];
#pragma unroll
    for (int i = 0; i < 16; ++i) { o[base + i] = excl; excl += loc[i]; }
}

// ---------------------------------------------------------------------------
// Kernel 2: fused frames+relu+segment-sum+normalize+mean+head.
// One wave per (allele, source). Lane task = (read, 4-consecutive-l group):
// 12 float4 global loads (each 128B line fully consumed by 8 lanes).
// W/bias are WAVE-UNIFORM and read from GLOBAL with uniform addresses ->
// compiler emits s_load into SGPRs (scalar cache): zero LDS-pipe traffic,
// zero VGPR cost for W. d-loop chunked by 4 so only ~52 W floats are
// SGPR-live. v[12] float4 (48 VGPR) + acc[32] stay; launch_bounds(256,3)
// caps VGPR at ~168 -> no spill (round-1 disaster: VGPR=256, 237MB spill).
// ---------------------------------------------------------------------------
__global__ __launch_bounds__(256, 3) void main_kernel(
    const float* __restrict__ t0, const float* __restrict__ t1,
    const float* __restrict__ W0, const float* __restrict__ b0,
    const float* __restrict__ W1, const float* __restrict__ b1,
    const float* __restrict__ W2, const float* __restrict__ b2,
    const int*  __restrict__ cnt0, const int* __restrict__ cnt1,
    const float* __restrict__ dm0, const float* __restrict__ dm1,
    const int*  __restrict__ offs0, const int* __restrict__ offs1,
    float* __restrict__ out)
{
    // tiny LDS stage only for the head weights (avoids per-wave tail loads)
    __shared__ float sW2[2 * 2 * DH];    // [NOUT][2D] flat = 128
    __shared__ float sB2[2];

    const int tid = threadIdx.x;
    if (tid < 2 * 2 * DH) sW2[tid] = W2[tid];
    if (tid < 2) sB2[tid] = b2[tid];
    __syncthreads();

    const int wave = tid >> 6;
    const int lane = tid & 63;
    const int p    = blockIdx.x * 4 + wave;   // 0..8191
    const int src  = p >> 12;                 // 0: source0, 1: source1
    const int a    = p & (A_ALLELES - 1);

    const float* __restrict__ tens = src ? t1 : t0;
    const int*   __restrict__ cnt  = src ? cnt1 : cnt0;
    const int*   __restrict__ offs = src ? offs1 : offs0;
    const float* __restrict__ dm   = src ? dm1 : dm0;
    const float* __restrict__ gW   = src ? W1 : W0;   // wave-uniform -> s_load
    const float* __restrict__ gB   = src ? b1 : b0;

    const int n     = cnt[a];
    const int start = offs[a];
    const float* base = tens + (size_t)start * (CCH * LW);

    float acc[DH];
#pragma unroll
    for (int d = 0; d < DH; ++d) acc[d] = 0.f;

    const int tasks = n * (LW / 4);           // (read, l-group-of-4) tasks
    for (int tsk = lane; tsk < tasks; tsk += 64) {
        const float* rp = base + (size_t)(tsk >> 3) * (CCH * LW) + (tsk & 7) * 4;
        float4 v[CCH];
#pragma unroll
        for (int c = 0; c < CCH; ++c)
            v[c] = *(const float4*)(rp + c * LW);

#pragma unroll 4
        for (int d = 0; d < DH; ++d) {
            const float* __restrict__ wr = gW + d * CCH;   // uniform addr
            const float bb = gB[d];                        // uniform addr
            float x0 = bb, x1 = bb, x2 = bb, x3 = bb;
#pragma unroll
            for (int c = 0; c < CCH; ++c) {
                const float wv = wr[c];                    // SGPR operand
                x0 = fmaf(v[c].x, wv, x0);
                x1 = fmaf(v[c].y, wv, x1);
                x2 = fmaf(v[c].z, wv, x2);
                x3 = fmaf(v[c].w, wv, x3);
            }
            acc[d] += (fmaxf(x0, 0.f) + fmaxf(x1, 0.f)) +
                      (fmaxf(x2, 0.f) + fmaxf(x3, 0.f));
        }
    }

    // wave butterfly reduction: every lane ends with the full per-allele sums
#pragma unroll
    for (int d = 0; d < DH; ++d) {
#pragma unroll
        for (int m = 32; m >= 1; m >>= 1)
            acc[d] += __shfl_xor(acc[d], m, 64);
    }

    const float scale = 1.f / (32.f * dm[a]);
    if (lane == 0) {
        float p0 = 0.f, p1 = 0.f;
#pragma unroll
        for (int d = 0; d < DH; ++d) {
            const float pv = acc[d] * scale;
            p0 = fmaf(pv, sW2[0 * 2 * DH + src * DH + d], p0);
            p1 = fmaf(pv, sW2[1 * 2 * DH + src * DH + d], p1);
        }
        if (src == 0) { p0 += sB2[0]; p1 += sB2[1]; }
        atomicAdd(&out[a * 2 + 0], p0);
        atomicAdd(&out[a * 2 + 1], p1);
    }
}

extern "C" void kernel_launch(void* const* d_in, const int* in_sizes, int n_in,
                              void* d_out, int out_size, void* d_ws, size_t ws_size,
                              hipStream_t stream) {
    const float* t0  = (const float*)d_in[0];
    const float* t1  = (const float*)d_in[1];
    const float* W0  = (const float*)d_in[2];
    const float* b0  = (const float*)d_in[3];
    const float* W1  = (const float*)d_in[4];
    const float* b1  = (const float*)d_in[5];
    const float* W2  = (const float*)d_in[6];
    const float* b2  = (const float*)d_in[7];
    const int*  cnt0 = (const int*)d_in[8];
    const int*  cnt1 = (const int*)d_in[9];
    // d_in[10] = numAllelesPerSite (unused by the reference math)
    const float* dm0 = (const float*)d_in[11];
    const float* dm1 = (const float*)d_in[12];

    int* offs0 = (int*)d_ws;
    int* offs1 = offs0 + A_ALLELES;

    hipMemsetAsync(d_out, 0, (size_t)out_size * sizeof(float), stream);
    scan_kernel<<<2, 256, 0, stream>>>(cnt0, cnt1, offs0, offs1);

    main_kernel<<<2048, 256, 0, stream>>>(
        t0, t1, W0, b0, W1, b1, W2, b2,
        cnt0, cnt1, dm0, dm1, offs0, offs1, (float*)d_out);
}

// Round 3
// 323.974 us; speedup vs baseline: 1.5230x; 1.5230x over previous
//
#include <hip/hip_runtime.h>

#define A_ALLELES 4096
#define CCH 12     // input channels
#define LW 32      // read window length
#define DH 32      // hidden dim

// ---------------------------------------------------------------------------
// Kernel 1: exclusive prefix-sum of the two per-allele read-count arrays.
// ---------------------------------------------------------------------------
__global__ __launch_bounds__(256) void scan_kernel(
    const int* __restrict__ c0, const int* __restrict__ c1,
    int* __restrict__ o0, int* __restrict__ o1)
{
    const int* c = (blockIdx.x == 0) ? c0 : c1;
    int*       o = (blockIdx.x == 0) ? o0 : o1;

    __shared__ int part[256];
    const int tid  = threadIdx.x;
    const int base = tid * 16;

    int loc[16];
    int s = 0;
#pragma unroll
    for (int i = 0; i < 16; ++i) { loc[i] = c[base + i]; s += loc[i]; }
    part[tid] = s;
    __syncthreads();

    for (int st = 1; st < 256; st <<= 1) {
        int v = (tid >= st) ? part[tid - st] : 0;
        __syncthreads();
        part[tid] += v;
        __syncthreads();
    }

    int excl = (tid == 0) ? 0 : part[tid - 1];
#pragma unroll
    for (int i = 0; i < 16; ++i) { o[base + i] = excl; excl += loc[i]; }
}

// ---------------------------------------------------------------------------
// Kernel 2: fused frames+relu+segment-sum+normalize+mean+head.
// One wave per (allele, source). src is BLOCK-uniform (blockIdx>>10) so the
// W/bias pointer select is provably uniform -> s_load into SGPRs (scalar
// cache), zero VGPR cost for W. d-loop FULLY unrolled so acc[] has
// compile-time indices -> registers (round 2 bug: partial unroll made acc
// dynamically indexed -> scratch -> 281MB write + 200MB extra fetch).
// Liveness ~95 VGPR; launch_bounds(256,4) caps at 128, 4 waves/SIMD.
// ---------------------------------------------------------------------------
__global__ __launch_bounds__(256, 4) void main_kernel(
    const float* __restrict__ t0, const float* __restrict__ t1,
    const float* __restrict__ W0, const float* __restrict__ b0,
    const float* __restrict__ W1, const float* __restrict__ b1,
    const float* __restrict__ W2, const float* __restrict__ b2,
    const int*  __restrict__ cnt0, const int* __restrict__ cnt1,
    const float* __restrict__ dm0, const float* __restrict__ dm1,
    const int*  __restrict__ offs0, const int* __restrict__ offs1,
    float* __restrict__ out)
{
    // tiny LDS stage only for the head weights (epilogue use)
    __shared__ float sW2[2 * 2 * DH];    // [NOUT][2D] flat = 128
    __shared__ float sB2[2];

    const int tid = threadIdx.x;
    if (tid < 2 * 2 * DH) sW2[tid] = W2[tid];
    if (tid < 2) sB2[tid] = b2[tid];
    __syncthreads();

    const int wave = tid >> 6;
    const int lane = tid & 63;
    const int src  = blockIdx.x >> 10;                     // block-uniform!
    const int a    = ((blockIdx.x & 1023) << 2) | wave;    // 0..4095

    const float* __restrict__ tens = src ? t1 : t0;
    const int*   __restrict__ cnt  = src ? cnt1 : cnt0;
    const int*   __restrict__ offs = src ? offs1 : offs0;
    const float* __restrict__ dm   = src ? dm1 : dm0;
    const float* __restrict__ gW   = src ? W1 : W0;   // uniform -> s_load
    const float* __restrict__ gB   = src ? b1 : b0;

    const int n     = cnt[a];
    const int start = offs[a];
    const float* base = tens + (size_t)start * (CCH * LW);

    float acc[DH];
#pragma unroll
    for (int d = 0; d < DH; ++d) acc[d] = 0.f;

    const int tasks = n * (LW / 4);           // (read, l-group-of-4) tasks
    for (int tsk = lane; tsk < tasks; tsk += 64) {
        const float* rp = base + (size_t)(tsk >> 3) * (CCH * LW) + (tsk & 7) * 4;
        float4 v[CCH];
#pragma unroll
        for (int c = 0; c < CCH; ++c)
            v[c] = *(const float4*)(rp + c * LW);

#pragma unroll
        for (int d = 0; d < DH; ++d) {
            const float bb = gB[d];                        // s_load
            float x0 = bb, x1 = bb, x2 = bb, x3 = bb;
#pragma unroll
            for (int c = 0; c < CCH; ++c) {
                const float wv = gW[d * CCH + c];          // s_load (SGPR)
                x0 = fmaf(v[c].x, wv, x0);
                x1 = fmaf(v[c].y, wv, x1);
                x2 = fmaf(v[c].z, wv, x2);
                x3 = fmaf(v[c].w, wv, x3);
            }
            acc[d] += (fmaxf(x0, 0.f) + fmaxf(x1, 0.f)) +
                      (fmaxf(x2, 0.f) + fmaxf(x3, 0.f));
        }
    }

    // wave butterfly reduction: every lane ends with the full per-allele sums
#pragma unroll
    for (int d = 0; d < DH; ++d) {
#pragma unroll
        for (int m = 32; m >= 1; m >>= 1)
            acc[d] += __shfl_xor(acc[d], m, 64);
    }

    const float scale = 1.f / (32.f * dm[a]);
    if (lane == 0) {
        float p0 = 0.f, p1 = 0.f;
#pragma unroll
        for (int d = 0; d < DH; ++d) {
            const float pv = acc[d] * scale;
            p0 = fmaf(pv, sW2[0 * 2 * DH + src * DH + d], p0);
            p1 = fmaf(pv, sW2[1 * 2 * DH + src * DH + d], p1);
        }
        if (src == 0) { p0 += sB2[0]; p1 += sB2[1]; }
        atomicAdd(&out[a * 2 + 0], p0);
        atomicAdd(&out[a * 2 + 1], p1);
    }
}

extern "C" void kernel_launch(void* const* d_in, const int* in_sizes, int n_in,
                              void* d_out, int out_size, void* d_ws, size_t ws_size,
                              hipStream_t stream) {
    const float* t0  = (const float*)d_in[0];
    const float* t1  = (const float*)d_in[1];
    const float* W0  = (const float*)d_in[2];
    const float* b0  = (const float*)d_in[3];
    const float* W1  = (const float*)d_in[4];
    const float* b1  = (const float*)d_in[5];
    const float* W2  = (const float*)d_in[6];
    const float* b2  = (const float*)d_in[7];
    const int*  cnt0 = (const int*)d_in[8];
    const int*  cnt1 = (const int*)d_in[9];
    // d_in[10] = numAllelesPerSite (unused by the reference math)
    const float* dm0 = (const float*)d_in[11];
    const float* dm1 = (const float*)d_in[12];

    int* offs0 = (int*)d_ws;
    int* offs1 = offs0 + A_ALLELES;

    hipMemsetAsync(d_out, 0, (size_t)out_size * sizeof(float), stream);
    scan_kernel<<<2, 256, 0, stream>>>(cnt0, cnt1, offs0, offs1);

    main_kernel<<<2048, 256, 0, stream>>>(
        t0, t1, W0, b0, W1, b1, W2, b2,
        cnt0, cnt1, dm0, dm1, offs0, offs1, (float*)d_out);
}

// Round 4
// 301.845 us; speedup vs baseline: 1.6347x; 1.0733x over previous
//
#include <hip/hip_runtime.h>

#define A_ALLELES 4096
#define CCH 12     // input channels
#define LW 32      // read window length
#define DH 32      // hidden dim
#define RDF (CCH * LW)          // floats per read = 384
#define LANES 64

typedef __attribute__((ext_vector_type(8))) short bf16x8;  // 8 bf16 in 4 VGPRs
typedef __attribute__((ext_vector_type(4))) float f32x4;

__device__ inline short f2bf(float f) {
    union { float f; unsigned u; } x; x.f = f;
    unsigned r = (x.u + 0x7fffu + ((x.u >> 16) & 1u)) >> 16;   // RNE
    return (short)r;
}

// ---------------------------------------------------------------------------
// Kernel 1: exclusive prefix-sum of the two per-allele read-count arrays.
// ---------------------------------------------------------------------------
__global__ __launch_bounds__(256) void scan_kernel(
    const int* __restrict__ c0, const int* __restrict__ c1,
    int* __restrict__ o0, int* __restrict__ o1)
{
    const int* c = (blockIdx.x == 0) ? c0 : c1;
    int*       o = (blockIdx.x == 0) ? o0 : o1;

    __shared__ int part[256];
    const int tid  = threadIdx.x;
    const int base = tid * 16;

    int loc[16];
    int s = 0;
#pragma unroll
    for (int i = 0; i < 16; ++i) { loc[i] = c[base + i]; s += loc[i]; }
    part[tid] = s;
    __syncthreads();

    for (int st = 1; st < 256; st <<= 1) {
        int v = (tid >= st) ? part[tid - st] : 0;
        __syncthreads();
        part[tid] += v;
        __syncthreads();
    }

    int excl = (tid == 0) ? 0 : part[tid - 1];
#pragma unroll
    for (int i = 0; i < 16; ++i) { o[base + i] = excl; excl += loc[i]; }
}

// ---------------------------------------------------------------------------
// Kernel 2: bf16-MFMA fused frames+relu+segsum+normalize+mean+head.
// One wave per (allele, source). Per read r (12c x 32l fp32 = 1536B):
//   - prefetch next read's globals (float4+float2/lane, coalesced)
//   - stage current read to WAVE-PRIVATE LDS (no barriers needed)
//   - A-frags (16x16x32, verified layout A[m=lane&15][k=quad*8+j]):
//     row=l, k=c (pad 12->32 with 0). B-frags = W rows (pad), bias via C.
//   - 4 MFMAs -> D[row=l, col=d], relu, acc into 2 scalars/lane.
// Epilogue: shfl over quads, scale 1/(32*dm), W2 head, 2 atomics.
// ---------------------------------------------------------------------------
__global__ __launch_bounds__(256, 4) void main_kernel(
    const float* __restrict__ t0, const float* __restrict__ t1,
    const float* __restrict__ W0, const float* __restrict__ b0,
    const float* __restrict__ W1, const float* __restrict__ b1,
    const float* __restrict__ W2, const float* __restrict__ b2,
    const int*  __restrict__ cnt0, const int* __restrict__ cnt1,
    const float* __restrict__ dm0, const float* __restrict__ dm1,
    const int*  __restrict__ offs0, const int* __restrict__ offs1,
    float* __restrict__ out)
{
    __shared__ float stage[4][RDF];      // per-wave private 1536B regions
    __shared__ float sW2[2 * 2 * DH];    // [NOUT][2D] flat = 128
    __shared__ float sB2[2];

    const int tid = threadIdx.x;
    if (tid < 2 * 2 * DH) sW2[tid] = W2[tid];
    if (tid < 2) sB2[tid] = b2[tid];
    __syncthreads();                     // once; loop below is barrier-free

    const int w    = tid >> 6;
    const int lane = tid & 63;
    const int src  = blockIdx.x >> 10;                  // block-uniform
    const int a    = ((blockIdx.x & 1023) << 2) | w;    // 0..4095

    const float* __restrict__ tens = src ? t1 : t0;
    const int*   __restrict__ cnt  = src ? cnt1 : cnt0;
    const int*   __restrict__ offs = src ? offs1 : offs0;
    const float* __restrict__ dm   = src ? dm1 : dm0;
    const float* __restrict__ gW   = src ? W1 : W0;
    const float* __restrict__ gB   = src ? b1 : b0;

    const int q  = lane >> 4;            // quad 0..3
    const int m  = lane & 15;            // row-within-tile / col-within-tile

    // --- B fragments (once per wave): B[k=c][n=d], lane holds col d=m(+16),
    //     elements j -> k = q*8+j; zero-pad k >= 12.
    bf16x8 bf0, bf1;
#pragma unroll
    for (int j = 0; j < 8; ++j) {
        const int c  = q * 8 + j;
        const int cs = (c < CCH) ? c : 0;            // safe in-bounds fetch
        const float w0v = gW[m * CCH + cs];
        const float w1v = gW[(16 + m) * CCH + cs];
        bf0[j] = (c < CCH) ? f2bf(w0v) : (short)0;
        bf1[j] = (c < CCH) ? f2bf(w1v) : (short)0;
    }
    // --- bias via MFMA C operand: C[row][col] = b[col]
    const float bv0 = gB[m], bv1 = gB[16 + m];
    const f32x4 cb0 = { bv0, bv0, bv0, bv0 };
    const f32x4 cb1 = { bv1, bv1, bv1, bv1 };

    const int n     = cnt[a];
    const int start = offs[a];
    const float* base = tens + (size_t)start * RDF;

    float acc0 = 0.f, acc1 = 0.f;        // sum of relu over this lane's rows

    // software pipeline: prefetch read 0
    float4 pfA = *(const float4*)(base + lane * 4);
    float2 pfB = *(const float2*)(base + 256 + lane * 2);

    for (int r = 0; r < n; ++r) {
        const float4 cA = pfA;
        const float2 cB = pfB;
        if (r + 1 < n) {
            const float* np = base + (size_t)(r + 1) * RDF;
            pfA = *(const float4*)(np + lane * 4);
            pfB = *(const float2*)(np + 256 + lane * 2);
        }
        // stage current read into wave-private LDS, layout [c][l] fp32
        *(float4*)&stage[w][lane * 4]       = cA;
        *(float2*)&stage[w][256 + lane * 2] = cB;
        // (same-wave DS ordering + compiler lgkm waits make this safe)

        // A fragments: A[m=l][k=c]; lane(q,m): elems j -> c = q*8+j
        bf16x8 a0, a1;
#pragma unroll
        for (int j = 0; j < 8; ++j) {
            const int c  = q * 8 + j;
            int cc = (q & 1) * 8 + j;                 // mirrored safe index
            if (cc > CCH - 1) cc = CCH - 1;           // 2-way-max bank alias
            const float v0 = stage[w][cc * LW + m];        // row l = m
            const float v1 = stage[w][cc * LW + 16 + m];   // row l = m+16
            a0[j] = (c < CCH) ? f2bf(v0) : (short)0;
            a1[j] = (c < CCH) ? f2bf(v1) : (short)0;
        }

        const f32x4 d00 = __builtin_amdgcn_mfma_f32_16x16x32_bf16(a0, bf0, cb0, 0, 0, 0);
        const f32x4 d01 = __builtin_amdgcn_mfma_f32_16x16x32_bf16(a0, bf1, cb1, 0, 0, 0);
        const f32x4 d10 = __builtin_amdgcn_mfma_f32_16x16x32_bf16(a1, bf0, cb0, 0, 0, 0);
        const f32x4 d11 = __builtin_amdgcn_mfma_f32_16x16x32_bf16(a1, bf1, cb1, 0, 0, 0);

#pragma unroll
        for (int k = 0; k < 4; ++k) {
            acc0 += fmaxf(d00[k], 0.f) + fmaxf(d10[k], 0.f);
            acc1 += fmaxf(d01[k], 0.f) + fmaxf(d11[k], 0.f);
        }
    }

    // combine quads: rows {4q..4q+3} x {l, l+16} -> full sum over 32 l
    acc0 += __shfl_xor(acc0, 16, 64);
    acc0 += __shfl_xor(acc0, 32, 64);
    acc1 += __shfl_xor(acc1, 16, 64);
    acc1 += __shfl_xor(acc1, 32, 64);

    const float scale = 1.f / (32.f * dm[a]);
    const float p0 = acc0 * scale;       // pooled[a, src*32 + m]
    const float p1 = acc1 * scale;       // pooled[a, src*32 + 16 + m]

    if (lane < 16) {
        float c0 = p0 * sW2[0 * 2 * DH + src * DH + m]
                 + p1 * sW2[0 * 2 * DH + src * DH + 16 + m];
        float c1 = p0 * sW2[1 * 2 * DH + src * DH + m]
                 + p1 * sW2[1 * 2 * DH + src * DH + 16 + m];
#pragma unroll
        for (int mm = 1; mm < 16; mm <<= 1) {
            c0 += __shfl_xor(c0, mm, 64);
            c1 += __shfl_xor(c1, mm, 64);
        }
        if (lane == 0) {
            if (src == 0) { c0 += sB2[0]; c1 += sB2[1]; }
            atomicAdd(&out[a * 2 + 0], c0);
            atomicAdd(&out[a * 2 + 1], c1);
        }
    }
}

extern "C" void kernel_launch(void* const* d_in, const int* in_sizes, int n_in,
                              void* d_out, int out_size, void* d_ws, size_t ws_size,
                              hipStream_t stream) {
    const float* t0  = (const float*)d_in[0];
    const float* t1  = (const float*)d_in[1];
    const float* W0  = (const float*)d_in[2];
    const float* b0  = (const float*)d_in[3];
    const float* W1  = (const float*)d_in[4];
    const float* b1  = (const float*)d_in[5];
    const float* W2  = (const float*)d_in[6];
    const float* b2  = (const float*)d_in[7];
    const int*  cnt0 = (const int*)d_in[8];
    const int*  cnt1 = (const int*)d_in[9];
    // d_in[10] = numAllelesPerSite (unused by the reference math)
    const float* dm0 = (const float*)d_in[11];
    const float* dm1 = (const float*)d_in[12];

    int* offs0 = (int*)d_ws;
    int* offs1 = offs0 + A_ALLELES;

    hipMemsetAsync(d_out, 0, (size_t)out_size * sizeof(float), stream);
    scan_kernel<<<2, 256, 0, stream>>>(cnt0, cnt1, offs0, offs1);

    main_kernel<<<2048, 256, 0, stream>>>(
        t0, t1, W0, b0, W1, b1, W2, b2,
        cnt0, cnt1, dm0, dm1, offs0, offs1, (float*)d_out);
}

// Round 5
// 301.813 us; speedup vs baseline: 1.6349x; 1.0001x over previous
//
#include <hip/hip_runtime.h>

#define A_ALLELES 4096
#define CCH 12     // input channels
#define LW 32      // read window length
#define DH 32      // hidden dim
#define RDF (CCH * LW)          // floats per read = 384

typedef __attribute__((ext_vector_type(8))) short bf16x8;  // 8 bf16 in 4 VGPRs
typedef __attribute__((ext_vector_type(4))) float f32x4;

// pack two fp32 -> two bf16 (round-half-up; differs from RNE only on exact
// ties, prob ~2^-16/value — irrelevant vs 2.35e-3 threshold). ~3-5 VALU.
__device__ inline unsigned pk2(float fa, float fb) {
    const unsigned a = __float_as_uint(fa), b = __float_as_uint(fb);
    return ((a + 0x8000u) >> 16) | ((b + 0x8000u) & 0xffff0000u);
}

// ---------------------------------------------------------------------------
// Kernel 1: exclusive prefix-sum of the two per-allele read-count arrays.
// ---------------------------------------------------------------------------
__global__ __launch_bounds__(256) void scan_kernel(
    const int* __restrict__ c0, const int* __restrict__ c1,
    int* __restrict__ o0, int* __restrict__ o1)
{
    const int* c = (blockIdx.x == 0) ? c0 : c1;
    int*       o = (blockIdx.x == 0) ? o0 : o1;

    __shared__ int part[256];
    const int tid  = threadIdx.x;
    const int base = tid * 16;

    int loc[16];
    int s = 0;
#pragma unroll
    for (int i = 0; i < 16; ++i) { loc[i] = c[base + i]; s += loc[i]; }
    part[tid] = s;
    __syncthreads();

    for (int st = 1; st < 256; st <<= 1) {
        int v = (tid >= st) ? part[tid - st] : 0;
        __syncthreads();
        part[tid] += v;
        __syncthreads();
    }

    int excl = (tid == 0) ? 0 : part[tid - 1];
#pragma unroll
    for (int i = 0; i < 16; ++i) { o[base + i] = excl; excl += loc[i]; }
}

// ---------------------------------------------------------------------------
// Kernel 2: bf16-MFMA, NO per-iteration LDS. A = W (A[m=d][k=c], hoisted),
// B = read tile straight from global: lane(q,m) loads t[c=q*8+j][l=m] and
// [l=16+m] via wave-uniform base + 8 hoisted per-lane offsets (+64B imm).
// c>=12 handled by clamped addresses + hoisted AND-masks on packed bf16.
// Bias enters via the MFMA C operand (row=d). D[row=d][col=l]: relu, then
// acc[d-reg] += over both l-tiles; epilogue shfl-reduces over m (l), folds
// 1/(32*depth) + W2 head, 2 atomics per (allele,src) wave.
// Fragment mappings identical to the round-4 PASSING kernel (roles swapped).
// ---------------------------------------------------------------------------
__global__ __launch_bounds__(256, 4) void main_kernel(
    const float* __restrict__ t0, const float* __restrict__ t1,
    const float* __restrict__ W0, const float* __restrict__ b0,
    const float* __restrict__ W1, const float* __restrict__ b1,
    const float* __restrict__ W2, const float* __restrict__ b2,
    const int*  __restrict__ cnt0, const int* __restrict__ cnt1,
    const float* __restrict__ dm0, const float* __restrict__ dm1,
    const int*  __restrict__ offs0, const int* __restrict__ offs1,
    float* __restrict__ out)
{
    __shared__ float sW2[2 * 2 * DH];    // [NOUT][2D] flat = 128
    __shared__ float sB2[2];

    const int tid = threadIdx.x;
    if (tid < 2 * 2 * DH) sW2[tid] = W2[tid];
    if (tid < 2) sB2[tid] = b2[tid];
    __syncthreads();                     // once; main loop is barrier-free

    const int w    = tid >> 6;
    const int lane = tid & 63;
    const int src  = blockIdx.x >> 10;                  // block-uniform
    const int a    = ((blockIdx.x & 1023) << 2) | w;    // 0..4095

    const float* __restrict__ tens = src ? t1 : t0;
    const int*   __restrict__ cnt  = src ? cnt1 : cnt0;
    const int*   __restrict__ offs = src ? offs1 : offs0;
    const float* __restrict__ dm   = src ? dm1 : dm0;
    const float* __restrict__ gW   = src ? W1 : W0;
    const float* __restrict__ gB   = src ? b1 : b0;

    const int q = lane >> 4;             // quad 0..3
    const int m = lane & 15;

    // ---- hoisted: A fragments from W (A[m=d][k=c]) + channel masks -------
    union { bf16x8 h; unsigned u[4]; } A0, A1;
    unsigned msk[4];
#pragma unroll
    for (int p = 0; p < 4; ++p) {
        const int c0 = q * 8 + 2 * p, c1 = c0 + 1;
        msk[p] = (c0 < CCH ? 0x0000ffffu : 0u) | (c1 < CCH ? 0xffff0000u : 0u);
        const int s0 = (c0 < CCH) ? c0 : 0, s1 = (c1 < CCH) ? c1 : 0;
        A0.u[p] = pk2(gW[m * CCH + s0],        gW[m * CCH + s1])        & msk[p];
        A1.u[p] = pk2(gW[(16 + m) * CCH + s0], gW[(16 + m) * CCH + s1]) & msk[p];
    }
    // ---- hoisted: bias via C operand, C[row=d=q*4+reg][*] = b[d] ---------
    f32x4 cb0, cb1;
#pragma unroll
    for (int k = 0; k < 4; ++k) {
        cb0[k] = gB[q * 4 + k];
        cb1[k] = gB[16 + q * 4 + k];
    }
    // ---- hoisted: per-lane load offsets (floats), c clamped to CCH-1 -----
    int off[8];
#pragma unroll
    for (int j = 0; j < 8; ++j) {
        int c = q * 8 + j;
        if (c > CCH - 1) c = CCH - 1;    // safe addr; garbage masked later
        off[j] = c * LW + m;
    }

    const int n     = cnt[a];
    const int start = offs[a];
    const float* rbase = tens + (size_t)start * RDF;

    float acc0[4] = {0.f, 0.f, 0.f, 0.f};   // d = q*4+reg
    float acc1[4] = {0.f, 0.f, 0.f, 0.f};   // d = 16+q*4+reg

#pragma unroll 2                              // n is always even (16 or 24)
    for (int r = 0; r < n; ++r) {
        float v0[8], v1[8];
#pragma unroll
        for (int j = 0; j < 8; ++j) {
            v0[j] = rbase[off[j]];            // B tile l = m
            v1[j] = rbase[off[j] + 16];       // B tile l = 16+m (imm +64B)
        }
        union { bf16x8 h; unsigned u[4]; } B0, B1;
#pragma unroll
        for (int p = 0; p < 4; ++p) {
            B0.u[p] = pk2(v0[2 * p], v0[2 * p + 1]) & msk[p];
            B1.u[p] = pk2(v1[2 * p], v1[2 * p + 1]) & msk[p];
        }

        const f32x4 d00 = __builtin_amdgcn_mfma_f32_16x16x32_bf16(A0.h, B0.h, cb0, 0, 0, 0);
        const f32x4 d01 = __builtin_amdgcn_mfma_f32_16x16x32_bf16(A0.h, B1.h, cb0, 0, 0, 0);
        const f32x4 d10 = __builtin_amdgcn_mfma_f32_16x16x32_bf16(A1.h, B0.h, cb1, 0, 0, 0);
        const f32x4 d11 = __builtin_amdgcn_mfma_f32_16x16x32_bf16(A1.h, B1.h, cb1, 0, 0, 0);

#pragma unroll
        for (int k = 0; k < 4; ++k) {
            acc0[k] += fmaxf(d00[k], 0.f) + fmaxf(d01[k], 0.f);
            acc1[k] += fmaxf(d10[k], 0.f) + fmaxf(d11[k], 0.f);
        }
        rbase += RDF;
    }

    // reduce over m (= l pairs) within each 16-lane quad
#pragma unroll
    for (int k = 0; k < 4; ++k) {
#pragma unroll
        for (int mm = 1; mm < 16; mm <<= 1) {
            acc0[k] += __shfl_xor(acc0[k], mm, 64);
            acc1[k] += __shfl_xor(acc1[k], mm, 64);
        }
    }

    const float scale = 1.f / (32.f * dm[a]);
    float c0 = 0.f, c1 = 0.f;
#pragma unroll
    for (int k = 0; k < 4; ++k) {
        const float p0 = acc0[k] * scale;     // pooled[a, src*32 + q*4+k]
        const float p1 = acc1[k] * scale;     // pooled[a, src*32 + 16+q*4+k]
        c0 += p0 * sW2[0 * 2 * DH + src * DH + q * 4 + k]
            + p1 * sW2[0 * 2 * DH + src * DH + 16 + q * 4 + k];
        c1 += p0 * sW2[1 * 2 * DH + src * DH + q * 4 + k]
            + p1 * sW2[1 * 2 * DH + src * DH + 16 + q * 4 + k];
    }
    // combine the four quads (each held 8 of the 32 d's)
    c0 += __shfl_xor(c0, 16, 64); c0 += __shfl_xor(c0, 32, 64);
    c1 += __shfl_xor(c1, 16, 64); c1 += __shfl_xor(c1, 32, 64);

    if (lane == 0) {
        if (src == 0) { c0 += sB2[0]; c1 += sB2[1]; }
        atomicAdd(&out[a * 2 + 0], c0);
        atomicAdd(&out[a * 2 + 1], c1);
    }
}

extern "C" void kernel_launch(void* const* d_in, const int* in_sizes, int n_in,
                              void* d_out, int out_size, void* d_ws, size_t ws_size,
                              hipStream_t stream) {
    const float* t0  = (const float*)d_in[0];
    const float* t1  = (const float*)d_in[1];
    const float* W0  = (const float*)d_in[2];
    const float* b0  = (const float*)d_in[3];
    const float* W1  = (const float*)d_in[4];
    const float* b1  = (const float*)d_in[5];
    const float* W2  = (const float*)d_in[6];
    const float* b2  = (const float*)d_in[7];
    const int*  cnt0 = (const int*)d_in[8];
    const int*  cnt1 = (const int*)d_in[9];
    // d_in[10] = numAllelesPerSite (unused by the reference math)
    const float* dm0 = (const float*)d_in[11];
    const float* dm1 = (const float*)d_in[12];

    int* offs0 = (int*)d_ws;
    int* offs1 = offs0 + A_ALLELES;

    hipMemsetAsync(d_out, 0, (size_t)out_size * sizeof(float), stream);
    scan_kernel<<<2, 256, 0, stream>>>(cnt0, cnt1, offs0, offs1);

    main_kernel<<<2048, 256, 0, stream>>>(
        t0, t1, W0, b0, W1, b1, W2, b2,
        cnt0, cnt1, dm0, dm1, offs0, offs1, (float*)d_out);
}

// Round 6
// 295.240 us; speedup vs baseline: 1.6713x; 1.0223x over previous
//
#include <hip/hip_runtime.h>

#define A_ALLELES 4096
#define CCH 12     // input channels
#define LW 32      // read window length
#define DH 32      // hidden dim
#define RDF (CCH * LW)          // floats per read = 384

typedef __attribute__((ext_vector_type(8)))  short bf16x8;   // 4 VGPRs
typedef __attribute__((ext_vector_type(16))) float f32x16;   // 16 VGPRs

// pack two fp32 -> two bf16 (round-half-up; differs from RNE only on ties)
__device__ inline unsigned pk2(float fa, float fb) {
    const unsigned a = __float_as_uint(fa), b = __float_as_uint(fb);
    return ((a + 0x8000u) >> 16) | ((b + 0x8000u) & 0xffff0000u);
}

// ---------------------------------------------------------------------------
// Kernel 1: exclusive prefix-sum of the two per-allele read-count arrays.
// ---------------------------------------------------------------------------
__global__ __launch_bounds__(256) void scan_kernel(
    const int* __restrict__ c0, const int* __restrict__ c1,
    int* __restrict__ o0, int* __restrict__ o1)
{
    const int* c = (blockIdx.x == 0) ? c0 : c1;
    int*       o = (blockIdx.x == 0) ? o0 : o1;

    __shared__ int part[256];
    const int tid  = threadIdx.x;
    const int base = tid * 16;

    int loc[16];
    int s = 0;
#pragma unroll
    for (int i = 0; i < 16; ++i) { loc[i] = c[base + i]; s += loc[i]; }
    part[tid] = s;
    __syncthreads();

    for (int st = 1; st < 256; st <<= 1) {
        int v = (tid >= st) ? part[tid - st] : 0;
        __syncthreads();
        part[tid] += v;
        __syncthreads();
    }

    int excl = (tid == 0) ? 0 : part[tid - 1];
#pragma unroll
    for (int i = 0; i < 16; ++i) { o[base + i] = excl; excl += loc[i]; }
}

// ---------------------------------------------------------------------------
// Kernel 2: 32x32x16 bf16 MFMA, ONE MFMA per read, depth-2 register pipeline.
// A = W (A[m=d=lane&31][k=(lane>>5)*8+j], zeros at k>=12). B = read tile
// from global: lane(h=lane>>5, l=lane&31) loads t[c][l] via two base ptrs
// (pLo: c=h*8+{0..3}; pHi: c=h?8..11:4..7 — h=1's j>=4 elems are dead
// (A zero) but in-bounds/finite). Bias via C operand. D[row=d][col=l] with
// row=(reg&3)+8*(reg>>2)+4*h (HW-verified). relu+acc in 16 regs; epilogue
// shfl-reduces over l, folds 1/(32*depth) + W2 head, 2 atomics/(a,src).
// Pipeline: pack bufK -> prefetch read r+2 into bufK -> MFMA -> acc; vmcnt
// wait for a buffer lands 2 reads later.
// ---------------------------------------------------------------------------
__global__ __launch_bounds__(256, 4) void main_kernel(
    const float* __restrict__ t0, const float* __restrict__ t1,
    const float* __restrict__ W0, const float* __restrict__ b0,
    const float* __restrict__ W1, const float* __restrict__ b1,
    const float* __restrict__ W2, const float* __restrict__ b2,
    const int*  __restrict__ cnt0, const int* __restrict__ cnt1,
    const float* __restrict__ dm0, const float* __restrict__ dm1,
    const int*  __restrict__ offs0, const int* __restrict__ offs1,
    float* __restrict__ out)
{
    __shared__ float sW2[2 * 2 * DH];    // [NOUT][2D] flat = 128
    __shared__ float sB2[2];

    const int tid = threadIdx.x;
    if (tid < 2 * 2 * DH) sW2[tid] = W2[tid];
    if (tid < 2) sB2[tid] = b2[tid];
    __syncthreads();                     // once; main loop is barrier-free

    const int w    = tid >> 6;
    const int lane = tid & 63;
    const int src  = blockIdx.x >> 10;                  // block-uniform
    const int a    = ((blockIdx.x & 1023) << 2) | w;    // 0..4095

    const float* __restrict__ tens = src ? t1 : t0;
    const int*   __restrict__ cnt  = src ? cnt1 : cnt0;
    const int*   __restrict__ offs = src ? offs1 : offs0;
    const float* __restrict__ dm   = src ? dm1 : dm0;
    const float* __restrict__ gW   = src ? W1 : W0;
    const float* __restrict__ gB   = src ? b1 : b0;

    const int l = lane & 31;             // B column / D column
    const int h = lane >> 5;             // k-half selector

    // ---- hoisted: A fragment from W: A[m=d=l][k=h*8+j], zero k>=12 -------
    union { bf16x8 v; unsigned u[4]; } Af;
#pragma unroll
    for (int p = 0; p < 4; ++p) {
        const int c0 = h * 8 + 2 * p, c1 = c0 + 1;
        const float f0 = (c0 < CCH) ? gW[l * CCH + c0] : 0.f;
        const float f1 = (c1 < CCH) ? gW[l * CCH + c1] : 0.f;
        Af.u[p] = pk2(f0, f1);
    }
    // ---- hoisted: bias via C operand: C[row=d][col] = b[d] ---------------
    f32x16 cb;
#pragma unroll
    for (int reg = 0; reg < 16; ++reg)
        cb[reg] = gB[(reg & 3) + 8 * (reg >> 2) + 4 * h];

    const int n     = cnt[a];
    const int start = offs[a];
    const float* rb = tens + (size_t)start * RDF;

    // two per-lane base pointers; all 8 loads use immediates {0,128,256,384}B
    const float* pLo = rb + l + h * 256;             // c = h*8 + j,  j=0..3
    const float* pHi = rb + l + (h ? 256 : 128);     // c = 4..7 (h0) / 8..11 (h1)

    float acc[16];
#pragma unroll
    for (int reg = 0; reg < 16; ++reg) acc[reg] = 0.f;

#define LOAD8(buf, P, W_)  do {                                     \
        buf[0] = pLo[(P) + 0];  buf[1] = pLo[(P) + 32];             \
        buf[2] = pLo[(P) + 64]; buf[3] = pLo[(P) + 96];             \
        buf[4] = pHi[(P) + 0];  buf[5] = pHi[(P) + 32];             \
        buf[6] = pHi[(P) + 64]; buf[7] = pHi[(P) + 96]; } while (0)

#define PACK_MFMA_ACC(buf) do {                                     \
        union { bf16x8 v; unsigned u[4]; } Bf;                      \
        Bf.u[0] = pk2(buf[0], buf[1]); Bf.u[1] = pk2(buf[2], buf[3]); \
        Bf.u[2] = pk2(buf[4], buf[5]); Bf.u[3] = pk2(buf[6], buf[7]); \
        const f32x16 D = __builtin_amdgcn_mfma_f32_32x32x16_bf16(   \
            Af.v, Bf.v, cb, 0, 0, 0);                               \
        _Pragma("unroll")                                           \
        for (int reg = 0; reg < 16; ++reg)                          \
            acc[reg] += fmaxf(D[reg], 0.f); } while (0)

    const int n2 = n & ~1;
    if (n2 >= 2) {
        float bA[8], bB[8];
        LOAD8(bA, 0, 0);                 // read 0
        LOAD8(bB, 384, 0);               // read 1
        const int iters = (n2 - 2) >> 1;
        for (int it = 0; it < iters; ++it) {
            {   // half A: process read 2it, prefetch read 2it+2
                union { bf16x8 v; unsigned u[4]; } Bf;
                Bf.u[0] = pk2(bA[0], bA[1]); Bf.u[1] = pk2(bA[2], bA[3]);
                Bf.u[2] = pk2(bA[4], bA[5]); Bf.u[3] = pk2(bA[6], bA[7]);
                LOAD8(bA, 768, 0);
                const f32x16 D = __builtin_amdgcn_mfma_f32_32x32x16_bf16(
                    Af.v, Bf.v, cb, 0, 0, 0);
#pragma unroll
                for (int reg = 0; reg < 16; ++reg) acc[reg] += fmaxf(D[reg], 0.f);
                pLo += 384; pHi += 384;
            }
            {   // half B: process read 2it+1, prefetch read 2it+3
                union { bf16x8 v; unsigned u[4]; } Bf;
                Bf.u[0] = pk2(bB[0], bB[1]); Bf.u[1] = pk2(bB[2], bB[3]);
                Bf.u[2] = pk2(bB[4], bB[5]); Bf.u[3] = pk2(bB[6], bB[7]);
                LOAD8(bB, 768, 0);
                const f32x16 D = __builtin_amdgcn_mfma_f32_32x32x16_bf16(
                    Af.v, Bf.v, cb, 0, 0, 0);
#pragma unroll
                for (int reg = 0; reg < 16; ++reg) acc[reg] += fmaxf(D[reg], 0.f);
                pLo += 384; pHi += 384;
            }
        }
        PACK_MFMA_ACC(bA);               // read n2-2
        PACK_MFMA_ACC(bB);               // read n2-1
    }
    if (n & 1) {                         // safety tail (counts are 16/24)
        const float* qLo = rb + (size_t)(n - 1) * RDF + l + h * 256;
        const float* qHi = rb + (size_t)(n - 1) * RDF + l + (h ? 256 : 128);
        float bT[8];
        bT[0] = qLo[0];  bT[1] = qLo[32]; bT[2] = qLo[64]; bT[3] = qLo[96];
        bT[4] = qHi[0];  bT[5] = qHi[32]; bT[6] = qHi[64]; bT[7] = qHi[96];
        PACK_MFMA_ACC(bT);
    }

    // reduce over l (cols): masks 1..16 stay within each 32-lane half
#pragma unroll
    for (int reg = 0; reg < 16; ++reg) {
#pragma unroll
        for (int mm = 1; mm < 32; mm <<= 1)
            acc[reg] += __shfl_xor(acc[reg], mm, 64);
    }

    const float scale = 1.f / (32.f * dm[a]);
    float c0s = 0.f, c1s = 0.f;
#pragma unroll
    for (int reg = 0; reg < 16; ++reg) {
        const int d = (reg & 3) + 8 * (reg >> 2) + 4 * h;
        const float pv = acc[reg] * scale;     // pooled[a, src*32 + d]
        c0s = fmaf(pv, sW2[0 * 2 * DH + src * DH + d], c0s);
        c1s = fmaf(pv, sW2[1 * 2 * DH + src * DH + d], c1s);
    }
    // combine the two h-halves (each held 16 of the 32 d's)
    c0s += __shfl_xor(c0s, 32, 64);
    c1s += __shfl_xor(c1s, 32, 64);

    if (lane == 0) {
        if (src == 0) { c0s += sB2[0]; c1s += sB2[1]; }
        atomicAdd(&out[a * 2 + 0], c0s);
        atomicAdd(&out[a * 2 + 1], c1s);
    }
#undef LOAD8
#undef PACK_MFMA_ACC
}

extern "C" void kernel_launch(void* const* d_in, const int* in_sizes, int n_in,
                              void* d_out, int out_size, void* d_ws, size_t ws_size,
                              hipStream_t stream) {
    const float* t0  = (const float*)d_in[0];
    const float* t1  = (const float*)d_in[1];
    const float* W0  = (const float*)d_in[2];
    const float* b0  = (const float*)d_in[3];
    const float* W1  = (const float*)d_in[4];
    const float* b1  = (const float*)d_in[5];
    const float* W2  = (const float*)d_in[6];
    const float* b2  = (const float*)d_in[7];
    const int*  cnt0 = (const int*)d_in[8];
    const int*  cnt1 = (const int*)d_in[9];
    // d_in[10] = numAllelesPerSite (unused by the reference math)
    const float* dm0 = (const float*)d_in[11];
    const float* dm1 = (const float*)d_in[12];

    int* offs0 = (int*)d_ws;
    int* offs1 = offs0 + A_ALLELES;

    hipMemsetAsync(d_out, 0, (size_t)out_size * sizeof(float), stream);
    scan_kernel<<<2, 256, 0, stream>>>(cnt0, cnt1, offs0, offs1);

    main_kernel<<<2048, 256, 0, stream>>>(
        t0, t1, W0, b0, W1, b1, W2, b2,
        cnt0, cnt1, dm0, dm1, offs0, offs1, (float*)d_out);
}